// Round 4
// baseline (441.080 us; speedup 1.0000x reference)
//
#include <hip/hip_runtime.h>
#include <hip/hip_bf16.h>
#include <math.h>

#define NN 100000
#define NE 625000
#define DIN 128
#define DH 256
#define NROWS 100096                      // NN padded to 128 (782 * 128)

#define SCAN_BS 1024
#define NB ((NN + SCAN_BS - 1) / SCAN_BS) // 98 scan blocks

typedef __attribute__((ext_vector_type(8))) short bf16x8;
typedef __attribute__((ext_vector_type(4))) float f32x4;

__device__ __forceinline__ unsigned short f2bf(float f) {
    unsigned u = __builtin_bit_cast(unsigned, f);
    u += 0x7fffu + ((u >> 16) & 1u);      // RNE
    return (unsigned short)(u >> 16);
}
__device__ __forceinline__ float bflo(unsigned u) {
    return __builtin_bit_cast(float, u << 16);
}
__device__ __forceinline__ float bfhi(unsigned u) {
    return __builtin_bit_cast(float, u & 0xffff0000u);
}
__device__ __forceinline__ unsigned packbf2(float a, float b) {
    return (unsigned)f2bf(a) | ((unsigned)f2bf(b) << 16);
}

// ---------------------------------------------------------------------------
// pack_w: w_cat[k][c] (k<128 -> w_l, else w_r) into MFMA B-fragment layout.
// Bp[((kt*16+ct)*64 + L)*8 + j] = bf16(w_cat[kt*32+(L>>4)*8+j][ct*16+(L&15)])
// ---------------------------------------------------------------------------
__global__ __launch_bounds__(256)
void pack_w(const float* __restrict__ w_l, const float* __restrict__ w_r,
            unsigned short* __restrict__ Bp) {
    int tid = blockIdx.x * 256 + threadIdx.x;   // 8192 total
    int kt = tid >> 10;
    int ct = (tid >> 6) & 15;
    int L = tid & 63;
    int k0 = kt * 32 + (L >> 4) * 8;
    int c = ct * 16 + (L & 15);
    unsigned short v[8];
#pragma unroll
    for (int j = 0; j < 8; ++j) {
        int k = k0 + j;
        float w = (k < 128) ? w_l[k * 256 + c] : w_r[(k - 128) * 256 + c];
        v[j] = f2bf(w);
    }
    *reinterpret_cast<bf16x8*>(Bp + (size_t)tid * 8) =
        *reinterpret_cast<const bf16x8*>(v);
}

// ---------------------------------------------------------------------------
// pack_heads: wt[o][k] = (o<7 ? w_p[k][o] : w_s[k][o-7])  -- float4-loadable
// ---------------------------------------------------------------------------
__global__ __launch_bounds__(256)
void pack_heads(const float* __restrict__ w_p, const float* __restrict__ w_s,
                float* __restrict__ wt) {
    int i = blockIdx.x * 256 + threadIdx.x;     // 13*256 = 3328
    if (i >= 13 * 256) return;
    int o = i >> 8, k = i & 255;
    wt[i] = (o < 7) ? w_p[k * 7 + o] : w_s[k * 6 + (o - 7)];
}

// ---------------------------------------------------------------------------
// xcast: A[n][128+j] = bf16(x[n][j])
// ---------------------------------------------------------------------------
__global__ __launch_bounds__(256)
void xcast(const float* __restrict__ x, unsigned short* __restrict__ A) {
    int idx = blockIdx.x * 256 + threadIdx.x;   // NN*32 threads
    if (idx >= NN * 32) return;
    int n = idx >> 5;
    int j4 = (idx & 31) * 4;
    float4 v = *reinterpret_cast<const float4*>(x + (size_t)n * DIN + j4);
    ushort4 o = { f2bf(v.x), f2bf(v.y), f2bf(v.z), f2bf(v.w) };
    *reinterpret_cast<ushort4*>(A + (size_t)n * 256 + 128 + j4) = o;
}

// ---------------------------------------------------------------------------
// CSR build
// ---------------------------------------------------------------------------
__global__ __launch_bounds__(256)
void sage_hist(const int* __restrict__ ei, int* __restrict__ deg) {
    int e = blockIdx.x * 256 + threadIdx.x;
    if (e >= NE) return;
    atomicAdd(&deg[ei[NE + e]], 1);
}

__global__ __launch_bounds__(256)
void sage_scan1(const int* __restrict__ deg, int* __restrict__ cursor,
                int* __restrict__ bsums) {
    __shared__ int ss[256];
    const int t = threadIdx.x;
    const int base = blockIdx.x * SCAN_BS + t * 4;
    int v[4];
#pragma unroll
    for (int j = 0; j < 4; ++j) v[j] = (base + j < NN) ? deg[base + j] : 0;
    int tsum = v[0] + v[1] + v[2] + v[3];
    ss[t] = tsum;
    __syncthreads();
    for (int o = 1; o < 256; o <<= 1) {
        int u = (t >= o) ? ss[t - o] : 0;
        __syncthreads();
        ss[t] += u;
        __syncthreads();
    }
    int run = ss[t] - tsum;
#pragma unroll
    for (int j = 0; j < 4; ++j) {
        if (base + j < NN) cursor[base + j] = run;
        run += v[j];
    }
    if (t == 255) bsums[blockIdx.x] = ss[255];
}

__global__ __launch_bounds__(128)
void sage_scan2(int* __restrict__ bsums) {
    __shared__ int ss[128];
    const int t = threadIdx.x;
    int v = (t < NB) ? bsums[t] : 0;
    ss[t] = v;
    __syncthreads();
    for (int o = 1; o < 128; o <<= 1) {
        int u = (t >= o) ? ss[t - o] : 0;
        __syncthreads();
        ss[t] += u;
        __syncthreads();
    }
    if (t < NB) bsums[t] = ss[t] - v;
}

__global__ __launch_bounds__(256)
void sage_scan3(int* __restrict__ cursor, const int* __restrict__ bsums) {
    int i = blockIdx.x * 256 + threadIdx.x;
    if (i >= NN) return;
    cursor[i] += bsums[i >> 10];
}

__global__ __launch_bounds__(256)
void sage_fill(const int* __restrict__ ei, int* __restrict__ cursor,
               int* __restrict__ elist) {
    int e = blockIdx.x * 256 + threadIdx.x;
    if (e >= NE) return;
    int p = atomicAdd(&cursor[ei[NE + e]], 1);
    elist[p] = ei[e];
}

// ---------------------------------------------------------------------------
// Gather-aggregate: quarter-wave (16 lanes) per node, lane owns 8 bf16 (16 B).
// Edge indices fetched cooperatively and broadcast via __shfl, so gathers are
// independent loads (no per-iteration elist latency in the chain).
// After sage_fill, cursor[n] = off[n] + deg[n]  ->  start = cursor[n]-deg[n].
// ---------------------------------------------------------------------------
__global__ __launch_bounds__(256)
void sage_aggregate(unsigned short* __restrict__ A,
                    const int* __restrict__ elist,
                    const int* __restrict__ cursor,
                    const int* __restrict__ deg) {
    const int t = threadIdx.x;
    const int n = blockIdx.x * 16 + (t >> 4);
    if (n >= NN) return;
    const int lane = t & 15;
    const int gbase = ((t >> 4) & 3) * 16;   // group base within wave
    const int d = deg[n];
    const int start = cursor[n] - d;
    float acc[8];
#pragma unroll
    for (int j = 0; j < 8; ++j) acc[j] = 0.f;
    int done = 0;
    while (done < d) {
        const int chunk = min(d - done, 16);
        int e = 0;
        if (lane < chunk) e = elist[start + done + lane];
        for (int j = 0; j < chunk; ++j) {
            const int src = __shfl(e, gbase + j, 64);
            const uint4 v = *reinterpret_cast<const uint4*>(
                A + (size_t)src * 256 + 128 + lane * 8);
            acc[0] += bflo(v.x); acc[1] += bfhi(v.x);
            acc[2] += bflo(v.y); acc[3] += bfhi(v.y);
            acc[4] += bflo(v.z); acc[5] += bfhi(v.z);
            acc[6] += bflo(v.w); acc[7] += bfhi(v.w);
        }
        done += chunk;
    }
    const float invd = (d > 0) ? 1.f / (float)d : 0.f;
    uint4 o;
    o.x = packbf2(acc[0] * invd, acc[1] * invd);
    o.y = packbf2(acc[2] * invd, acc[3] * invd);
    o.z = packbf2(acc[4] * invd, acc[5] * invd);
    o.w = packbf2(acc[6] * invd, acc[7] * invd);
    *reinterpret_cast<uint4*>(A + (size_t)n * 256 + lane * 8) = o;
}

// ---------------------------------------------------------------------------
// MFMA GEMM with B in LDS. Block = 256 thr (4 waves), M-tile = 128 rows.
// Wave owns 32 rows (2 rowsets of 16); each ds_read_b128 of a B fragment
// feeds 2 MFMAs. LDS: B staged once (128 KB), then the hs tile (133 KB)
// aliases the same region after the K-loop. out13 sits above hs.
// ---------------------------------------------------------------------------
__global__ __launch_bounds__(256, 1)
void sage_gemm_mfma(const unsigned short* __restrict__ A,
                    const unsigned short* __restrict__ Bp,
                    const float* __restrict__ b_l,
                    const float* __restrict__ wt,
                    const float* __restrict__ b_p,
                    const float* __restrict__ b_s,
                    float* __restrict__ out) {
    __shared__ __align__(16) unsigned char smem[139776];
    unsigned short* Bs = (unsigned short*)smem;          // [128 KB] B frags
    float* hs = (float*)smem;                            // [128][260] after K-loop
    float* o13 = (float*)(smem + 133120);                // [128][13]

    const int t = threadIdx.x;
    const int wave = t >> 6;
    const int L = t & 63;
    const int q = L >> 4;
    const int m15 = L & 15;
    const int node0 = blockIdx.x * 128;
    const int rowbase = node0 + wave * 32;

    // ---- stage B (131072 B) into LDS: 32 rounds x 256 thr x 16 B ----
    {
        const uint4* gsrc = reinterpret_cast<const uint4*>(Bp);
        uint4* ldst = reinterpret_cast<uint4*>(Bs);
#pragma unroll 8
        for (int r = 0; r < 32; ++r) {
            ldst[r * 256 + t] = gsrc[r * 256 + t];
        }
    }

    // ---- A fragments: 2 rowsets x 8 k-tiles, dwordx4 each ----
    const unsigned short* ar0 = A + (size_t)(rowbase + m15) * 256;
    const unsigned short* ar1 = ar0 + 16 * 256;
    bf16x8 a0[8], a1[8];
#pragma unroll
    for (int kt = 0; kt < 8; ++kt) {
        a0[kt] = *reinterpret_cast<const bf16x8*>(ar0 + kt * 32 + q * 8);
        a1[kt] = *reinterpret_cast<const bf16x8*>(ar1 + kt * 32 + q * 8);
    }

    f32x4 acc0[16], acc1[16];
#pragma unroll
    for (int ct = 0; ct < 16; ++ct) {
        acc0[ct] = (f32x4){0.f, 0.f, 0.f, 0.f};
        acc1[ct] = (f32x4){0.f, 0.f, 0.f, 0.f};
    }

    __syncthreads();   // B staged

#pragma unroll
    for (int kt = 0; kt < 8; ++kt) {
#pragma unroll
        for (int ct = 0; ct < 16; ++ct) {
            bf16x8 b = *reinterpret_cast<const bf16x8*>(
                Bs + ((size_t)(kt * 16 + ct) * 64 + L) * 8);
            acc0[ct] = __builtin_amdgcn_mfma_f32_16x16x32_bf16(a0[kt], b, acc0[ct], 0, 0, 0);
            acc1[ct] = __builtin_amdgcn_mfma_f32_16x16x32_bf16(a1[kt], b, acc1[ct], 0, 0, 0);
        }
    }

    __syncthreads();   // everyone done reading Bs; safe to overwrite with hs

    // ---- epilogue: bias + relu -> hs (stride 260) ----
    // lane L holds D[row = q*4 + r][col = ct*16 + m15] per tile
#pragma unroll
    for (int ct = 0; ct < 16; ++ct) {
        const int c = ct * 16 + m15;
        const float blv = b_l[c];
        const int r0 = wave * 32 + q * 4;
#pragma unroll
        for (int r = 0; r < 4; ++r) {
            hs[(r0 + r) * 260 + c] = fmaxf(acc0[ct][r] + blv, 0.f);
            hs[(r0 + 16 + r) * 260 + c] = fmaxf(acc1[ct][r] + blv, 0.f);
        }
    }
    __syncthreads();

    // ---- heads: 128 nodes x 13 outputs, f32, wt is [13][256] ----
    for (int idx = t; idx < 128 * 13; idx += 256) {
        const int m = idx / 13;
        const int o = idx % 13;
        const float* hrow = hs + (size_t)m * 260;
        const float* wrow = wt + (size_t)o * 256;
        float s = 0.f;
        for (int k = 0; k < 256; k += 4) {
            float4 hv = *reinterpret_cast<const float4*>(hrow + k);
            float4 wv = *reinterpret_cast<const float4*>(wrow + k);
            s += hv.x * wv.x + hv.y * wv.y + hv.z * wv.z + hv.w * wv.w;
        }
        s += (o < 7) ? b_p[o] : b_s[o - 7];
        o13[m * 13 + o] = s;
    }
    __syncthreads();

    // ---- log_softmax + write ----
    if (t < 128) {
        const int gnode = node0 + t;
        if (gnode < NN) {
            float v[7], mx = -1e30f;
#pragma unroll
            for (int j = 0; j < 7; ++j) { v[j] = o13[t * 13 + j]; mx = fmaxf(mx, v[j]); }
            float sum = 0.f;
#pragma unroll
            for (int j = 0; j < 7; ++j) sum += expf(v[j] - mx);
            const float lse = mx + logf(sum);
#pragma unroll
            for (int j = 0; j < 7; ++j) out[(size_t)gnode * 7 + j] = v[j] - lse;

            float u[6], mx2 = -1e30f;
#pragma unroll
            for (int j = 0; j < 6; ++j) { u[j] = o13[t * 13 + 7 + j]; mx2 = fmaxf(mx2, u[j]); }
            float sum2 = 0.f;
#pragma unroll
            for (int j = 0; j < 6; ++j) sum2 += expf(u[j] - mx2);
            const float lse2 = mx2 + logf(sum2);
#pragma unroll
            for (int j = 0; j < 6; ++j) out[(size_t)NN * 7 + (size_t)gnode * 6 + j] = u[j] - lse2;
        }
    }
}

extern "C" void kernel_launch(void* const* d_in, const int* in_sizes, int n_in,
                              void* d_out, int out_size, void* d_ws, size_t ws_size,
                              hipStream_t stream) {
    const float* x   = (const float*)d_in[0];
    const int*   ei  = (const int*)d_in[1];
    const float* w_l = (const float*)d_in[2];
    const float* b_l = (const float*)d_in[3];
    const float* w_r = (const float*)d_in[4];
    const float* w_p = (const float*)d_in[5];
    const float* b_p = (const float*)d_in[6];
    const float* w_s = (const float*)d_in[7];
    const float* b_s = (const float*)d_in[8];
    float* out = (float*)d_out;

    // workspace layout (~54.8 MB)
    unsigned short* A  = (unsigned short*)d_ws;      // [NROWS][256] bf16: [mean|x]
    unsigned short* Bp = A + (size_t)NROWS * 256;    // 65536 bf16 (128 KB) MFMA layout
    float* wt   = (float*)(Bp + 65536);              // [13][256] head weights^T
    int* deg    = (int*)(wt + 13 * 256);             // NN
    int* cursor = deg + NN;                          // NN
    int* bsums  = cursor + NN;                       // 128
    int* elist  = bsums + 128;                       // NE

    hipMemsetAsync(deg, 0, NN * sizeof(int), stream);

    pack_w<<<32, 256, 0, stream>>>(w_l, w_r, Bp);
    pack_heads<<<13, 256, 0, stream>>>(w_p, w_s, wt);
    xcast<<<(NN * 32 + 255) / 256, 256, 0, stream>>>(x, A);

    sage_hist<<<(NE + 255) / 256, 256, 0, stream>>>(ei, deg);
    sage_scan1<<<NB, 256, 0, stream>>>(deg, cursor, bsums);
    sage_scan2<<<1, 128, 0, stream>>>(bsums);
    sage_scan3<<<(NN + 255) / 256, 256, 0, stream>>>(cursor, bsums);
    sage_fill<<<(NE + 255) / 256, 256, 0, stream>>>(ei, cursor, elist);
    sage_aggregate<<<(NN + 15) / 16, 256, 0, stream>>>(A, elist, cursor, deg);

    sage_gemm_mfma<<<NROWS / 128, 256, 0, stream>>>(A, Bp, b_l, wt, b_p, b_s, out);
}

// Round 5
// 240.465 us; speedup vs baseline: 1.8343x; 1.8343x over previous
//
#include <hip/hip_runtime.h>
#include <hip/hip_bf16.h>
#include <math.h>

#define NN 100000
#define NE 625000
#define DIN 128
#define DH 256
#define NROWS 100096                      // NN padded to 128 (782 * 128)

#define SCAN_BS 1024
#define NB ((NN + SCAN_BS - 1) / SCAN_BS) // 98 scan blocks

#define HS_STRIDE 264                     // bf16 elems; 528 B = 33*16, 16B-aligned rows

typedef __attribute__((ext_vector_type(8))) short bf16x8;
typedef __attribute__((ext_vector_type(4))) float f32x4;

__device__ __forceinline__ unsigned short f2bf(float f) {
    unsigned u = __builtin_bit_cast(unsigned, f);
    u += 0x7fffu + ((u >> 16) & 1u);      // RNE
    return (unsigned short)(u >> 16);
}
__device__ __forceinline__ float bflo(unsigned u) {
    return __builtin_bit_cast(float, u << 16);
}
__device__ __forceinline__ float bfhi(unsigned u) {
    return __builtin_bit_cast(float, u & 0xffff0000u);
}
__device__ __forceinline__ unsigned packbf2(float a, float b) {
    return (unsigned)f2bf(a) | ((unsigned)f2bf(b) << 16);
}

// ---------------------------------------------------------------------------
// pack_w: w_cat[k][c] (k<128 -> w_l, else w_r) into MFMA B-fragment layout.
// Bp[((kt*16+ct)*64 + L)*8 + j] = bf16(w_cat[kt*32+(L>>4)*8+j][ct*16+(L&15)])
// ---------------------------------------------------------------------------
__global__ __launch_bounds__(256)
void pack_w(const float* __restrict__ w_l, const float* __restrict__ w_r,
            unsigned short* __restrict__ Bp) {
    int tid = blockIdx.x * 256 + threadIdx.x;   // 8192 total
    int kt = tid >> 10;
    int ct = (tid >> 6) & 15;
    int L = tid & 63;
    int k0 = kt * 32 + (L >> 4) * 8;
    int c = ct * 16 + (L & 15);
    unsigned short v[8];
#pragma unroll
    for (int j = 0; j < 8; ++j) {
        int k = k0 + j;
        float w = (k < 128) ? w_l[k * 256 + c] : w_r[(k - 128) * 256 + c];
        v[j] = f2bf(w);
    }
    *reinterpret_cast<bf16x8*>(Bp + (size_t)tid * 8) =
        *reinterpret_cast<const bf16x8*>(v);
}

// ---------------------------------------------------------------------------
// pack_heads: head weights [256 x 16] (cols 0..6 = w_p, 7..12 = w_s, rest 0)
// into MFMA B-fragment layout (8 k-tiles, 1 col-tile):
// whp[(kt*64+L)*8 + j] = bf16(wt_cat[kt*32+(L>>4)*8+j][L&15])
// Also bhc[16]: packed head biases.
// ---------------------------------------------------------------------------
__global__ __launch_bounds__(256)
void pack_heads(const float* __restrict__ w_p, const float* __restrict__ w_s,
                const float* __restrict__ b_p, const float* __restrict__ b_s,
                unsigned short* __restrict__ whp, float* __restrict__ bhc) {
    int tid = blockIdx.x * 256 + threadIdx.x;   // 512 total
    int kt = tid >> 6;
    int L = tid & 63;
    int k0 = kt * 32 + (L >> 4) * 8;
    int c = L & 15;
    unsigned short v[8];
#pragma unroll
    for (int j = 0; j < 8; ++j) {
        int k = k0 + j;
        float w = (c < 7) ? w_p[k * 7 + c] : (c < 13 ? w_s[k * 6 + (c - 7)] : 0.f);
        v[j] = f2bf(w);
    }
    *reinterpret_cast<bf16x8*>(whp + (size_t)tid * 8) =
        *reinterpret_cast<const bf16x8*>(v);
    if (tid < 16)
        bhc[tid] = (tid < 7) ? b_p[tid] : (tid < 13 ? b_s[tid - 7] : 0.f);
}

// ---------------------------------------------------------------------------
// xcast: A[n][128+j] = bf16(x[n][j])
// ---------------------------------------------------------------------------
__global__ __launch_bounds__(256)
void xcast(const float* __restrict__ x, unsigned short* __restrict__ A) {
    int idx = blockIdx.x * 256 + threadIdx.x;   // NN*32 threads
    if (idx >= NN * 32) return;
    int n = idx >> 5;
    int j4 = (idx & 31) * 4;
    float4 v = *reinterpret_cast<const float4*>(x + (size_t)n * DIN + j4);
    ushort4 o = { f2bf(v.x), f2bf(v.y), f2bf(v.z), f2bf(v.w) };
    *reinterpret_cast<ushort4*>(A + (size_t)n * 256 + 128 + j4) = o;
}

// ---------------------------------------------------------------------------
// CSR build
// ---------------------------------------------------------------------------
__global__ __launch_bounds__(256)
void sage_hist(const int* __restrict__ ei, int* __restrict__ deg) {
    int e = blockIdx.x * 256 + threadIdx.x;
    if (e >= NE) return;
    atomicAdd(&deg[ei[NE + e]], 1);
}

__global__ __launch_bounds__(256)
void sage_scan1(const int* __restrict__ deg, int* __restrict__ cursor,
                int* __restrict__ bsums) {
    __shared__ int ss[256];
    const int t = threadIdx.x;
    const int base = blockIdx.x * SCAN_BS + t * 4;
    int v[4];
#pragma unroll
    for (int j = 0; j < 4; ++j) v[j] = (base + j < NN) ? deg[base + j] : 0;
    int tsum = v[0] + v[1] + v[2] + v[3];
    ss[t] = tsum;
    __syncthreads();
    for (int o = 1; o < 256; o <<= 1) {
        int u = (t >= o) ? ss[t - o] : 0;
        __syncthreads();
        ss[t] += u;
        __syncthreads();
    }
    int run = ss[t] - tsum;
#pragma unroll
    for (int j = 0; j < 4; ++j) {
        if (base + j < NN) cursor[base + j] = run;
        run += v[j];
    }
    if (t == 255) bsums[blockIdx.x] = ss[255];
}

__global__ __launch_bounds__(128)
void sage_scan2(int* __restrict__ bsums) {
    __shared__ int ss[128];
    const int t = threadIdx.x;
    int v = (t < NB) ? bsums[t] : 0;
    ss[t] = v;
    __syncthreads();
    for (int o = 1; o < 128; o <<= 1) {
        int u = (t >= o) ? ss[t - o] : 0;
        __syncthreads();
        ss[t] += u;
        __syncthreads();
    }
    if (t < NB) bsums[t] = ss[t] - v;
}

__global__ __launch_bounds__(256)
void sage_scan3(int* __restrict__ cursor, const int* __restrict__ bsums) {
    int i = blockIdx.x * 256 + threadIdx.x;
    if (i >= NN) return;
    cursor[i] += bsums[i >> 10];
}

__global__ __launch_bounds__(256)
void sage_fill(const int* __restrict__ ei, int* __restrict__ cursor,
               int* __restrict__ elist) {
    int e = blockIdx.x * 256 + threadIdx.x;
    if (e >= NE) return;
    int p = atomicAdd(&cursor[ei[NE + e]], 1);
    elist[p] = ei[e];
}

// ---------------------------------------------------------------------------
// Gather-aggregate: quarter-wave (16 lanes) per node, lane owns 8 bf16 (16 B).
// ---------------------------------------------------------------------------
__global__ __launch_bounds__(256)
void sage_aggregate(unsigned short* __restrict__ A,
                    const int* __restrict__ elist,
                    const int* __restrict__ cursor,
                    const int* __restrict__ deg) {
    const int t = threadIdx.x;
    const int n = blockIdx.x * 16 + (t >> 4);
    if (n >= NN) return;
    const int lane = t & 15;
    const int gbase = ((t >> 4) & 3) * 16;
    const int d = deg[n];
    const int start = cursor[n] - d;
    float acc[8];
#pragma unroll
    for (int j = 0; j < 8; ++j) acc[j] = 0.f;
    int done = 0;
    while (done < d) {
        const int chunk = min(d - done, 16);
        int e = 0;
        if (lane < chunk) e = elist[start + done + lane];
        for (int j = 0; j < chunk; ++j) {
            const int src = __shfl(e, gbase + j, 64);
            const uint4 v = *reinterpret_cast<const uint4*>(
                A + (size_t)src * 256 + 128 + lane * 8);
            acc[0] += bflo(v.x); acc[1] += bfhi(v.x);
            acc[2] += bflo(v.y); acc[3] += bfhi(v.y);
            acc[4] += bflo(v.z); acc[5] += bfhi(v.z);
            acc[6] += bflo(v.w); acc[7] += bfhi(v.w);
        }
        done += chunk;
    }
    const float invd = (d > 0) ? 1.f / (float)d : 0.f;
    uint4 o;
    o.x = packbf2(acc[0] * invd, acc[1] * invd);
    o.y = packbf2(acc[2] * invd, acc[3] * invd);
    o.z = packbf2(acc[4] * invd, acc[5] * invd);
    o.w = packbf2(acc[6] * invd, acc[7] * invd);
    *reinterpret_cast<uint4*>(A + (size_t)n * 256 + lane * 8) = o;
}

// ---------------------------------------------------------------------------
// MFMA GEMM. Block = 512 thr (8 waves), M-tile = 128 rows; wave owns 16 rows.
// B (128 KB) staged once into LDS; after the K-loop the same region is reused
// as the bf16 h-tile (stride 264). Heads computed by MFMA (B-frag packed wt).
// 1 block/CU but 8 waves -> 2 waves/SIMD for latency hiding.
// ---------------------------------------------------------------------------
__global__ __launch_bounds__(512, 1)
void sage_gemm_mfma(const unsigned short* __restrict__ A,
                    const unsigned short* __restrict__ Bp,
                    const float* __restrict__ b_l,
                    const unsigned short* __restrict__ whp,
                    const float* __restrict__ bhc,
                    float* __restrict__ out) {
    __shared__ __align__(16) unsigned char smem[139776];
    unsigned short* Bs = (unsigned short*)smem;          // 128 KB B frags
    unsigned short* hs = (unsigned short*)smem;          // [128][264] bf16 (aliased)
    float* o13 = (float*)(smem + 131072);                // [128][17]

    const int t = threadIdx.x;
    const int wave = t >> 6;
    const int L = t & 63;
    const int q = L >> 4;
    const int m15 = L & 15;
    const int node0 = blockIdx.x * 128;
    const int rowbase = node0 + wave * 16;

    // ---- stage B (131072 B): 16 rounds x 512 thr x 16 B ----
    {
        const uint4* gsrc = reinterpret_cast<const uint4*>(Bp);
        uint4* ldst = reinterpret_cast<uint4*>(Bs);
#pragma unroll
        for (int r = 0; r < 16; ++r)
            ldst[r * 512 + t] = gsrc[r * 512 + t];
    }

    // ---- A fragments: 8 k-tiles, dwordx4 each ----
    const unsigned short* arow = A + (size_t)(rowbase + m15) * 256;
    bf16x8 afrag[8];
#pragma unroll
    for (int kt = 0; kt < 8; ++kt)
        afrag[kt] = *reinterpret_cast<const bf16x8*>(arow + kt * 32 + q * 8);

    f32x4 acc[16];
#pragma unroll
    for (int ct = 0; ct < 16; ++ct) acc[ct] = (f32x4){0.f, 0.f, 0.f, 0.f};

    __syncthreads();   // B staged

#pragma unroll
    for (int kt = 0; kt < 8; ++kt) {
#pragma unroll
        for (int ct = 0; ct < 16; ++ct) {
            bf16x8 b = *reinterpret_cast<const bf16x8*>(
                Bs + ((size_t)(kt * 16 + ct) * 64 + L) * 8);
            acc[ct] = __builtin_amdgcn_mfma_f32_16x16x32_bf16(afrag[kt], b, acc[ct], 0, 0, 0);
        }
    }

    __syncthreads();   // all waves done reading Bs; reuse as hs

    // ---- epilogue: bias + relu -> hs bf16 (stride 264) ----
    // lane L holds D[row = q*4 + r][col = ct*16 + m15]
#pragma unroll
    for (int ct = 0; ct < 16; ++ct) {
        const int c = ct * 16 + m15;
        const float blv = b_l[c];
        const int r0 = wave * 16 + q * 4;
#pragma unroll
        for (int r = 0; r < 4; ++r)
            hs[(r0 + r) * HS_STRIDE + c] = f2bf(fmaxf(acc[ct][r] + blv, 0.f));
    }
    __syncthreads();

    // ---- heads via MFMA: wave's 16 rows x 16 (13 used) cols, K=256 ----
    {
        f32x4 acch = (f32x4){0.f, 0.f, 0.f, 0.f};
        const unsigned short* hrow = hs + (size_t)(wave * 16 + m15) * HS_STRIDE;
#pragma unroll
        for (int kt = 0; kt < 8; ++kt) {
            bf16x8 ah = *reinterpret_cast<const bf16x8*>(hrow + kt * 32 + q * 8);
            bf16x8 bh = *reinterpret_cast<const bf16x8*>(whp + ((size_t)(kt * 64 + L)) * 8);
            acch = __builtin_amdgcn_mfma_f32_16x16x32_bf16(ah, bh, acch, 0, 0, 0);
        }
        const float bh = (m15 < 13) ? bhc[m15] : 0.f;
        if (m15 < 13) {
#pragma unroll
            for (int r = 0; r < 4; ++r)
                o13[(wave * 16 + q * 4 + r) * 17 + m15] = acch[r] + bh;
        }
    }
    __syncthreads();

    // ---- log_softmax + write ----
    if (t < 128) {
        const int gnode = node0 + t;
        if (gnode < NN) {
            float v[7], mx = -1e30f;
#pragma unroll
            for (int j = 0; j < 7; ++j) { v[j] = o13[t * 17 + j]; mx = fmaxf(mx, v[j]); }
            float sum = 0.f;
#pragma unroll
            for (int j = 0; j < 7; ++j) sum += expf(v[j] - mx);
            const float lse = mx + logf(sum);
#pragma unroll
            for (int j = 0; j < 7; ++j) out[(size_t)gnode * 7 + j] = v[j] - lse;

            float u[6], mx2 = -1e30f;
#pragma unroll
            for (int j = 0; j < 6; ++j) { u[j] = o13[t * 17 + 7 + j]; mx2 = fmaxf(mx2, u[j]); }
            float sum2 = 0.f;
#pragma unroll
            for (int j = 0; j < 6; ++j) sum2 += expf(u[j] - mx2);
            const float lse2 = mx2 + logf(sum2);
#pragma unroll
            for (int j = 0; j < 6; ++j) out[(size_t)NN * 7 + (size_t)gnode * 6 + j] = u[j] - lse2;
        }
    }
}

extern "C" void kernel_launch(void* const* d_in, const int* in_sizes, int n_in,
                              void* d_out, int out_size, void* d_ws, size_t ws_size,
                              hipStream_t stream) {
    const float* x   = (const float*)d_in[0];
    const int*   ei  = (const int*)d_in[1];
    const float* w_l = (const float*)d_in[2];
    const float* b_l = (const float*)d_in[3];
    const float* w_r = (const float*)d_in[4];
    const float* w_p = (const float*)d_in[5];
    const float* b_p = (const float*)d_in[6];
    const float* w_s = (const float*)d_in[7];
    const float* b_s = (const float*)d_in[8];
    float* out = (float*)d_out;

    // workspace layout (~54.8 MB)
    unsigned short* A   = (unsigned short*)d_ws;     // [NROWS][256] bf16: [mean|x]
    unsigned short* Bp  = A + (size_t)NROWS * 256;   // 65536 bf16 MFMA layout
    unsigned short* whp = Bp + 65536;                // 4096 bf16 head B-frags
    float* bhc  = (float*)(whp + 4096);              // [16] head biases
    int* deg    = (int*)(bhc + 16);                  // NN
    int* cursor = deg + NN;                          // NN
    int* bsums  = cursor + NN;                       // 128
    int* elist  = bsums + 128;                       // NE

    hipMemsetAsync(deg, 0, NN * sizeof(int), stream);

    pack_w<<<32, 256, 0, stream>>>(w_l, w_r, Bp);
    pack_heads<<<2, 256, 0, stream>>>(w_p, w_s, b_p, b_s, whp, bhc);
    xcast<<<(NN * 32 + 255) / 256, 256, 0, stream>>>(x, A);

    sage_hist<<<(NE + 255) / 256, 256, 0, stream>>>(ei, deg);
    sage_scan1<<<NB, 256, 0, stream>>>(deg, cursor, bsums);
    sage_scan2<<<1, 128, 0, stream>>>(bsums);
    sage_scan3<<<(NN + 255) / 256, 256, 0, stream>>>(cursor, bsums);
    sage_fill<<<(NE + 255) / 256, 256, 0, stream>>>(ei, cursor, elist);
    sage_aggregate<<<(NN + 15) / 16, 256, 0, stream>>>(A, elist, cursor, deg);

    sage_gemm_mfma<<<NROWS / 128, 512, 0, stream>>>(A, Bp, b_l, whp, bhc, out);
}

// Round 6
// 233.953 us; speedup vs baseline: 1.8853x; 1.0278x over previous
//
#include <hip/hip_runtime.h>
#include <hip/hip_bf16.h>
#include <math.h>

#define NN 100000
#define NE 625000
#define DIN 128
#define DH 256
#define NROWS 100096                      // NN padded to 128 (782 * 128)

#define SCAN_BS 1024
#define NB ((NN + SCAN_BS - 1) / SCAN_BS) // 98 scan blocks

#define HS_STRIDE 264                     // bf16 elems; 528 B rows, 16B-aligned

// prep kernel block ranges
#define XCAST_BLOCKS 12500                // NN*32 / 256 exactly
#define HIST_BLOCKS  2442
#define PACKW_BLOCKS 32
#define PACKH_BLOCKS 2
#define PREP_BLOCKS  (XCAST_BLOCKS + HIST_BLOCKS + PACKW_BLOCKS + PACKH_BLOCKS)

typedef __attribute__((ext_vector_type(8))) short bf16x8;
typedef __attribute__((ext_vector_type(4))) float f32x4;

__device__ __forceinline__ unsigned short f2bf(float f) {
    unsigned u = __builtin_bit_cast(unsigned, f);
    u += 0x7fffu + ((u >> 16) & 1u);      // RNE
    return (unsigned short)(u >> 16);
}
__device__ __forceinline__ float bflo(unsigned u) {
    return __builtin_bit_cast(float, u << 16);
}
__device__ __forceinline__ float bfhi(unsigned u) {
    return __builtin_bit_cast(float, u & 0xffff0000u);
}

// ---------------------------------------------------------------------------
// prep: fused xcast | hist | pack_w | pack_heads (independent block ranges)
// ---------------------------------------------------------------------------
__global__ __launch_bounds__(256)
void prep(const float* __restrict__ x, const int* __restrict__ ei,
          const float* __restrict__ w_l, const float* __restrict__ w_r,
          const float* __restrict__ w_p, const float* __restrict__ w_s,
          const float* __restrict__ b_p, const float* __restrict__ b_s,
          unsigned short* __restrict__ A, unsigned short* __restrict__ Bp,
          unsigned short* __restrict__ whp, float* __restrict__ bhc,
          int* __restrict__ deg) {
    const int b = blockIdx.x;
    const int t = threadIdx.x;

    if (b < XCAST_BLOCKS) {
        // xcast: A[n][128+j] = bf16(x[n][j]);  grid covers NN*32 exactly
        int idx = b * 256 + t;
        int n = idx >> 5;
        int j4 = (idx & 31) * 4;
        float4 v = *reinterpret_cast<const float4*>(x + (size_t)n * DIN + j4);
        ushort4 o = { f2bf(v.x), f2bf(v.y), f2bf(v.z), f2bf(v.w) };
        *reinterpret_cast<ushort4*>(A + (size_t)n * 256 + 128 + j4) = o;
    } else if (b < XCAST_BLOCKS + HIST_BLOCKS) {
        int e = (b - XCAST_BLOCKS) * 256 + t;
        if (e < NE) atomicAdd(&deg[ei[NE + e]], 1);
    } else if (b < XCAST_BLOCKS + HIST_BLOCKS + PACKW_BLOCKS) {
        // pack_w into MFMA B-fragment layout
        int tid = (b - XCAST_BLOCKS - HIST_BLOCKS) * 256 + t;   // 8192
        int kt = tid >> 10;
        int ct = (tid >> 6) & 15;
        int L = tid & 63;
        int k0 = kt * 32 + (L >> 4) * 8;
        int c = ct * 16 + (L & 15);
        unsigned short v[8];
#pragma unroll
        for (int j = 0; j < 8; ++j) {
            int k = k0 + j;
            float w = (k < 128) ? w_l[k * 256 + c] : w_r[(k - 128) * 256 + c];
            v[j] = f2bf(w);
        }
        *reinterpret_cast<bf16x8*>(Bp + (size_t)tid * 8) =
            *reinterpret_cast<const bf16x8*>(v);
    } else {
        // pack_heads: [256 x 16] (cols 0..6 w_p, 7..12 w_s, rest 0) B-frags
        int tid = (b - XCAST_BLOCKS - HIST_BLOCKS - PACKW_BLOCKS) * 256 + t; // 512
        int kt = tid >> 6;
        int L = tid & 63;
        int k0 = kt * 32 + (L >> 4) * 8;
        int c = L & 15;
        unsigned short v[8];
#pragma unroll
        for (int j = 0; j < 8; ++j) {
            int k = k0 + j;
            float w = (c < 7) ? w_p[k * 7 + c] : (c < 13 ? w_s[k * 6 + (c - 7)] : 0.f);
            v[j] = f2bf(w);
        }
        *reinterpret_cast<bf16x8*>(whp + (size_t)tid * 8) =
            *reinterpret_cast<const bf16x8*>(v);
        if (tid < 16)
            bhc[tid] = (tid < 7) ? b_p[tid] : (tid < 13 ? b_s[tid - 7] : 0.f);
    }
}

// ---------------------------------------------------------------------------
// CSR scans: cursor <- per-block-local exclusive prefix of deg; bsums totals
// ---------------------------------------------------------------------------
__global__ __launch_bounds__(256)
void sage_scan1(const int* __restrict__ deg, int* __restrict__ cursor,
                int* __restrict__ bsums) {
    __shared__ int ss[256];
    const int t = threadIdx.x;
    const int base = blockIdx.x * SCAN_BS + t * 4;
    int v[4];
#pragma unroll
    for (int j = 0; j < 4; ++j) v[j] = (base + j < NN) ? deg[base + j] : 0;
    int tsum = v[0] + v[1] + v[2] + v[3];
    ss[t] = tsum;
    __syncthreads();
    for (int o = 1; o < 256; o <<= 1) {
        int u = (t >= o) ? ss[t - o] : 0;
        __syncthreads();
        ss[t] += u;
        __syncthreads();
    }
    int run = ss[t] - tsum;
#pragma unroll
    for (int j = 0; j < 4; ++j) {
        if (base + j < NN) cursor[base + j] = run;
        run += v[j];
    }
    if (t == 255) bsums[blockIdx.x] = ss[255];
}

__global__ __launch_bounds__(128)
void sage_scan2(int* __restrict__ bsums) {
    __shared__ int ss[128];
    const int t = threadIdx.x;
    int v = (t < NB) ? bsums[t] : 0;
    ss[t] = v;
    __syncthreads();
    for (int o = 1; o < 128; o <<= 1) {
        int u = (t >= o) ? ss[t - o] : 0;
        __syncthreads();
        ss[t] += u;
        __syncthreads();
    }
    if (t < NB) bsums[t] = ss[t] - v;
}

// ---------------------------------------------------------------------------
// CSR fill with folded block offsets: pos = bsums[dst>>10] + local cursor++
// After this, cursor[n] = local_prefix[n] + deg[n].
// ---------------------------------------------------------------------------
__global__ __launch_bounds__(256)
void sage_fill(const int* __restrict__ ei, int* __restrict__ cursor,
               const int* __restrict__ bsums, int* __restrict__ elist) {
    int e = blockIdx.x * 256 + threadIdx.x;
    if (e >= NE) return;
    int dst = ei[NE + e];
    int p = bsums[dst >> 10] + atomicAdd(&cursor[dst], 1);
    elist[p] = ei[e];
}

// ---------------------------------------------------------------------------
// Fused gather-mean + MFMA GEMM + heads + log_softmax.
// Block = 512 thr (8 waves), M-tile 128; wave owns 16 rows.
// mean[n] is consumed only by row n, so each lane gathers exactly the mean
// dims its A-fragment needs: lane L (q=L>>4, m15=L&15) accumulates dims
// kt*32+q*8+{0..7}, kt=0..3, of row m15 -- 4x16B loads per neighbor, the
// 4 q-lanes of a row together covering the full 256B x-row (coalesced).
// B (128 KB) staged to LDS once; hs tile aliases it after the K-loop.
// ---------------------------------------------------------------------------
__global__ __launch_bounds__(512, 1)
void sage_gemm_fused(const unsigned short* __restrict__ A,
                     const unsigned short* __restrict__ Bp,
                     const float* __restrict__ b_l,
                     const unsigned short* __restrict__ whp,
                     const float* __restrict__ bhc,
                     const int* __restrict__ elist,
                     const int* __restrict__ cursor,
                     const int* __restrict__ bsums,
                     const int* __restrict__ deg,
                     float* __restrict__ out) {
    __shared__ __align__(16) unsigned char smem[139776];
    unsigned short* Bs = (unsigned short*)smem;          // 128 KB B frags
    unsigned short* hs = (unsigned short*)smem;          // [128][264] bf16 (alias)
    float* o13 = (float*)(smem + 131072);                // [128][17]

    const int t = threadIdx.x;
    const int wave = t >> 6;
    const int L = t & 63;
    const int q = L >> 4;
    const int m15 = L & 15;
    const int node0 = blockIdx.x * 128;
    const int rowbase = node0 + wave * 16;
    const int n = rowbase + m15;          // row this lane's A-frags belong to

    // ---- stage B (131072 B): 16 rounds x 512 thr x 16 B (reg roundtrip) ----
    {
        const uint4* gsrc = reinterpret_cast<const uint4*>(Bp);
        uint4* ldst = reinterpret_cast<uint4*>(Bs);
#pragma unroll
        for (int r = 0; r < 16; ++r)
            ldst[r * 512 + t] = gsrc[r * 512 + t];
    }

    // ---- x-half A fragments (kt = 4..7): own row, direct loads ----
    const unsigned short* arow = A + (size_t)n * 256;
    bf16x8 afrag[8];
#pragma unroll
    for (int kt = 4; kt < 8; ++kt)
        afrag[kt] = *reinterpret_cast<const bf16x8*>(arow + kt * 32 + q * 8);

    // ---- gather-mean for kt = 0..3: this lane's 32 dims of row n ----
    {
        float macc[32];
#pragma unroll
        for (int j = 0; j < 32; ++j) macc[j] = 0.f;
        int d = 0, start = 0;
        if (n < NN) {
            d = deg[n];
            start = bsums[n >> 10] + cursor[n] - d;   // cursor = local_pfx + deg
        }
        int srcN = (d > 0) ? elist[start] : 0;
        for (int i = 0; i < d; ++i) {
            const int src = srcN;
            if (i + 1 < d) srcN = elist[start + i + 1];
            const unsigned short* xr = A + (size_t)src * 256 + 128 + q * 8;
            const uint4 v0 = *reinterpret_cast<const uint4*>(xr);
            const uint4 v1 = *reinterpret_cast<const uint4*>(xr + 32);
            const uint4 v2 = *reinterpret_cast<const uint4*>(xr + 64);
            const uint4 v3 = *reinterpret_cast<const uint4*>(xr + 96);
            macc[0]  += bflo(v0.x); macc[1]  += bfhi(v0.x);
            macc[2]  += bflo(v0.y); macc[3]  += bfhi(v0.y);
            macc[4]  += bflo(v0.z); macc[5]  += bfhi(v0.z);
            macc[6]  += bflo(v0.w); macc[7]  += bfhi(v0.w);
            macc[8]  += bflo(v1.x); macc[9]  += bfhi(v1.x);
            macc[10] += bflo(v1.y); macc[11] += bfhi(v1.y);
            macc[12] += bflo(v1.z); macc[13] += bfhi(v1.z);
            macc[14] += bflo(v1.w); macc[15] += bfhi(v1.w);
            macc[16] += bflo(v2.x); macc[17] += bfhi(v2.x);
            macc[18] += bflo(v2.y); macc[19] += bfhi(v2.y);
            macc[20] += bflo(v2.z); macc[21] += bfhi(v2.z);
            macc[22] += bflo(v2.w); macc[23] += bfhi(v2.w);
            macc[24] += bflo(v3.x); macc[25] += bfhi(v3.x);
            macc[26] += bflo(v3.y); macc[27] += bfhi(v3.y);
            macc[28] += bflo(v3.z); macc[29] += bfhi(v3.z);
            macc[30] += bflo(v3.w); macc[31] += bfhi(v3.w);
        }
        const float invd = (d > 0) ? 1.f / (float)d : 0.f;
#pragma unroll
        for (int kt = 0; kt < 4; ++kt) {
            unsigned short vv[8];
#pragma unroll
            for (int j = 0; j < 8; ++j) vv[j] = f2bf(macc[kt * 8 + j] * invd);
            afrag[kt] = *reinterpret_cast<const bf16x8*>(vv);
        }
    }

    f32x4 acc[16];
#pragma unroll
    for (int ct = 0; ct < 16; ++ct) acc[ct] = (f32x4){0.f, 0.f, 0.f, 0.f};

    __syncthreads();   // B staged (and all gathers done)

#pragma unroll
    for (int kt = 0; kt < 8; ++kt) {
#pragma unroll
        for (int ct = 0; ct < 16; ++ct) {
            bf16x8 b = *reinterpret_cast<const bf16x8*>(
                Bs + ((size_t)(kt * 16 + ct) * 64 + L) * 8);
            acc[ct] = __builtin_amdgcn_mfma_f32_16x16x32_bf16(afrag[kt], b, acc[ct], 0, 0, 0);
        }
    }

    __syncthreads();   // all waves done reading Bs; reuse as hs

    // ---- epilogue: bias + relu -> hs bf16 (stride 264) ----
    // lane L holds D[row = q*4 + r][col = ct*16 + m15]
#pragma unroll
    for (int ct = 0; ct < 16; ++ct) {
        const int c = ct * 16 + m15;
        const float blv = b_l[c];
        const int r0 = wave * 16 + q * 4;
#pragma unroll
        for (int r = 0; r < 4; ++r)
            hs[(r0 + r) * HS_STRIDE + c] = f2bf(fmaxf(acc[ct][r] + blv, 0.f));
    }
    __syncthreads();

    // ---- heads via MFMA: wave's 16 rows x 16 (13 used) cols, K=256 ----
    {
        f32x4 acch = (f32x4){0.f, 0.f, 0.f, 0.f};
        const unsigned short* hrow = hs + (size_t)(wave * 16 + m15) * HS_STRIDE;
#pragma unroll
        for (int kt = 0; kt < 8; ++kt) {
            bf16x8 ah = *reinterpret_cast<const bf16x8*>(hrow + kt * 32 + q * 8);
            bf16x8 bh = *reinterpret_cast<const bf16x8*>(whp + ((size_t)(kt * 64 + L)) * 8);
            acch = __builtin_amdgcn_mfma_f32_16x16x32_bf16(ah, bh, acch, 0, 0, 0);
        }
        if (m15 < 13) {
            const float bh = bhc[m15];
#pragma unroll
            for (int r = 0; r < 4; ++r)
                o13[(wave * 16 + q * 4 + r) * 17 + m15] = acch[r] + bh;
        }
    }
    __syncthreads();

    // ---- log_softmax + write ----
    if (t < 128) {
        const int gnode = node0 + t;
        if (gnode < NN) {
            float v[7], mx = -1e30f;
#pragma unroll
            for (int j = 0; j < 7; ++j) { v[j] = o13[t * 17 + j]; mx = fmaxf(mx, v[j]); }
            float sum = 0.f;
#pragma unroll
            for (int j = 0; j < 7; ++j) sum += expf(v[j] - mx);
            const float lse = mx + logf(sum);
#pragma unroll
            for (int j = 0; j < 7; ++j) out[(size_t)gnode * 7 + j] = v[j] - lse;

            float u[6], mx2 = -1e30f;
#pragma unroll
            for (int j = 0; j < 6; ++j) { u[j] = o13[t * 17 + 7 + j]; mx2 = fmaxf(mx2, u[j]); }
            float sum2 = 0.f;
#pragma unroll
            for (int j = 0; j < 6; ++j) sum2 += expf(u[j] - mx2);
            const float lse2 = mx2 + logf(sum2);
#pragma unroll
            for (int j = 0; j < 6; ++j) out[(size_t)NN * 7 + (size_t)gnode * 6 + j] = u[j] - lse2;
        }
    }
}

extern "C" void kernel_launch(void* const* d_in, const int* in_sizes, int n_in,
                              void* d_out, int out_size, void* d_ws, size_t ws_size,
                              hipStream_t stream) {
    const float* x   = (const float*)d_in[0];
    const int*   ei  = (const int*)d_in[1];
    const float* w_l = (const float*)d_in[2];
    const float* b_l = (const float*)d_in[3];
    const float* w_r = (const float*)d_in[4];
    const float* w_p = (const float*)d_in[5];
    const float* b_p = (const float*)d_in[6];
    const float* w_s = (const float*)d_in[7];
    const float* b_s = (const float*)d_in[8];
    float* out = (float*)d_out;

    // workspace layout (~54.7 MB)
    unsigned short* A   = (unsigned short*)d_ws;     // [NROWS][256] bf16: [mean|x]
    unsigned short* Bp  = A + (size_t)NROWS * 256;   // 65536 bf16 MFMA layout
    unsigned short* whp = Bp + 65536;                // 4096 bf16 head B-frags
    float* bhc  = (float*)(whp + 4096);              // [16] head biases
    int* deg    = (int*)(bhc + 16);                  // NN
    int* cursor = deg + NN;                          // NN (local prefix)
    int* bsums  = cursor + NN;                       // 128
    int* elist  = bsums + 128;                       // NE

    hipMemsetAsync(deg, 0, NN * sizeof(int), stream);

    prep<<<PREP_BLOCKS, 256, 0, stream>>>(x, ei, w_l, w_r, w_p, w_s, b_p, b_s,
                                          A, Bp, whp, bhc, deg);
    sage_scan1<<<NB, 256, 0, stream>>>(deg, cursor, bsums);
    sage_scan2<<<1, 128, 0, stream>>>(bsums);
    sage_fill<<<(NE + 255) / 256, 256, 0, stream>>>(ei, cursor, bsums, elist);

    sage_gemm_fused<<<NROWS / 128, 512, 0, stream>>>(A, Bp, b_l, whp, bhc,
                                                     elist, cursor, bsums, deg, out);
}